// Round 11
// baseline (68.746 us; speedup 1.0000x reference)
//
#include <hip/hip_runtime.h>
#include <math.h>

namespace {

constexpr int N  = 4096;
constexpr int E  = 256;
constexpr int H  = 8;
constexpr int DH = 32;
constexpr int BS = 8;
// fold 1/sqrt(DH) and log2(e): softmax in exp2 domain, no max subtraction
// (f32-safe: |s*CL| realistic max ~16, overflow at 127 -> 27 sigma margin)
constexpr float CL = 0.17677669529663687f * 1.4426950408889634f;

typedef __bf16 bf16x8 __attribute__((ext_vector_type(8)));
typedef __bf16 bf16x4 __attribute__((ext_vector_type(4)));
typedef float  f32x4  __attribute__((ext_vector_type(4)));

#if __has_builtin(__builtin_amdgcn_exp2f)
#define EXP2F(x) __builtin_amdgcn_exp2f(x)
#else
#define EXP2F(x) __expf((x) * 0.6931471805599453f)
#endif

// async global->LDS DMA, 16B per lane; LDS dest is wave-uniform base + lane*16
#define GLOAD16(G, L)                                              \
  __builtin_amdgcn_global_load_lds(                                \
      (const __attribute__((address_space(1))) void*)(G),          \
      (__attribute__((address_space(3))) void*)(L), 16, 0, 0)

__device__ inline bf16x8 pack8(float4 a, float4 b) {
  bf16x8 r;
  r[0] = (__bf16)a.x; r[1] = (__bf16)a.y; r[2] = (__bf16)a.z; r[3] = (__bf16)a.w;
  r[4] = (__bf16)b.x; r[5] = (__bf16)b.y; r[6] = (__bf16)b.z; r[7] = (__bf16)b.w;
  return r;
}

// ---------------------------------------------------------------------------
// prep: one memory-bound pass producing all bf16 operands. (frozen)
// ---------------------------------------------------------------------------
__global__ __launch_bounds__(256) void prep_kernel(
    const float* __restrict__ x, const float* __restrict__ pe,
    const int* __restrict__ xb,
    const float* __restrict__ Wq, const float* __restrict__ Wk,
    const float* __restrict__ Wv, const float* __restrict__ Wo,
    __bf16* __restrict__ xpe, __bf16* __restrict__ xv,
    __bf16* __restrict__ wb, int* __restrict__ seg)
{
  const int bid = blockIdx.x;
  if (bid < 512) {
    const size_t e0 = ((size_t)bid * 256 + threadIdx.x) * 8;
    float4 a0 = *(const float4*)(x + e0);
    float4 a1 = *(const float4*)(x + e0 + 4);
    const float4 p0 = *(const float4*)(pe + e0);
    const float4 p1 = *(const float4*)(pe + e0 + 4);
    *reinterpret_cast<bf16x8*>(xv + e0) = pack8(a0, a1);
    a0.x += p0.x; a0.y += p0.y; a0.z += p0.z; a0.w += p0.w;
    a1.x += p1.x; a1.y += p1.y; a1.z += p1.z; a1.w += p1.w;
    *reinterpret_cast<bf16x8*>(xpe + e0) = pack8(a0, a1);
  } else if (bid < 640) {
    const size_t e0 = ((size_t)(bid - 512) * 256 + threadIdx.x) * 8;
    const int mat = (int)(e0 >> 16);
    const size_t off = e0 & 65535;
    const float* __restrict__ W =
        (mat == 0) ? Wq : (mat == 1) ? Wk : (mat == 2) ? Wv : Wo;
    *reinterpret_cast<bf16x8*>(wb + e0) =
        pack8(*(const float4*)(W + off), *(const float4*)(W + off + 4));
  } else {
    if (threadIdx.x <= BS) {
      const int t = threadIdx.x;
      int lo = 0, hi = N;
      while (lo < hi) { int mid = (lo + hi) >> 1; if (xb[mid] < t) lo = mid + 1; else hi = mid; }
      seg[t] = lo;
    }
  }
}

// ---------------------------------------------------------------------------
// MFMA QKV with explicit W double-buffer. (frozen from round 9/10)
// ---------------------------------------------------------------------------
__global__ __launch_bounds__(256, 2) void qkv_mfma(
    const __bf16* __restrict__ xpe, const __bf16* __restrict__ xv,
    const __bf16* __restrict__ wb,
    const float* __restrict__ bq, const float* __restrict__ bk,
    const float* __restrict__ bv,
    __bf16* __restrict__ qo, __bf16* __restrict__ ko,
    __bf16* __restrict__ vt)
{
  const int mat  = blockIdx.y;
  const int m0   = (blockIdx.x >> 1) * 16;
  const int half = blockIdx.x & 1;
  const int wv   = threadIdx.x >> 6;
  const int lane = threadIdx.x & 63;
  const int l15  = lane & 15, g = lane >> 4;
  const int cb0  = half * 128 + wv * 32;

  const __bf16* __restrict__ A = (mat < 2) ? xpe : xv;
  const __bf16* __restrict__ W = wb + (size_t)mat * E * E;
  const int mrow = m0 + l15;

  const __bf16* __restrict__ w0p = W + (size_t)(cb0 + l15) * E + 8 * g;
  const __bf16* __restrict__ w1p = W + (size_t)(cb0 + 16 + l15) * E + 8 * g;

  bf16x8 af[8];
#pragma unroll
  for (int kk = 0; kk < 8; ++kk)
    af[kk] = *reinterpret_cast<const bf16x8*>(A + (size_t)mrow * E + kk * 32 + 8 * g);

  f32x4 acc0 = {0.f, 0.f, 0.f, 0.f};
  f32x4 acc1 = {0.f, 0.f, 0.f, 0.f};

  bf16x8 wA0 = *reinterpret_cast<const bf16x8*>(w0p);
  bf16x8 wA1 = *reinterpret_cast<const bf16x8*>(w1p);

#pragma unroll
  for (int kk = 0; kk < 8; ++kk) {
    bf16x8 wB0, wB1;
    if (kk < 7) {
      wB0 = *reinterpret_cast<const bf16x8*>(w0p + (kk + 1) * 32);
      wB1 = *reinterpret_cast<const bf16x8*>(w1p + (kk + 1) * 32);
    }
    acc0 = __builtin_amdgcn_mfma_f32_16x16x32_bf16(wA0, af[kk], acc0, 0, 0, 0);
    acc1 = __builtin_amdgcn_mfma_f32_16x16x32_bf16(wA1, af[kk], acc1, 0, 0, 0);
    if (kk < 7) { wA0 = wB0; wA1 = wB1; }
  }

  if (mat < 2) {
    __bf16* __restrict__ outb = mat ? ko : qo;
    const float* __restrict__ bi = mat ? bk : bq;
    f32x4 accs[2] = {acc0, acc1};
#pragma unroll
    for (int nt = 0; nt < 2; ++nt) {
      const int n_base = cb0 + nt * 16 + 4 * g;
      const float4 bb = *(const float4*)(bi + n_base);
      bf16x4 o;
      o.x = (__bf16)(accs[nt][0] + bb.x);
      o.y = (__bf16)(accs[nt][1] + bb.y);
      o.z = (__bf16)(accs[nt][2] + bb.z);
      o.w = (__bf16)(accs[nt][3] + bb.w);
      *reinterpret_cast<bf16x4*>(outb + (size_t)mrow * E + n_base) = o;
    }
  } else {
    f32x4 accs[2] = {acc0, acc1};
#pragma unroll
    for (int nt = 0; nt < 2; ++nt) {
      const int n_base = cb0 + nt * 16 + 4 * g;
      const float4 bb = *(const float4*)(bv + n_base);
      const float bbr[4] = {bb.x, bb.y, bb.z, bb.w};
#pragma unroll
      for (int r = 0; r < 4; ++r)
        vt[(size_t)(n_base + r) * N + mrow] = (__bf16)(accs[nt][r] + bbr[r]);
    }
  }
}

// ---------------------------------------------------------------------------
// Fused attention + projection + residual + LayerNorm — DEEP-PIPELINED LDS.
// Block = 16 query rows, 512 threads = 8 waves, wave = head.
// KVBLK=32 (16 fine tiles per ~512-key segment), TRIPLE-buffered LDS tiles,
// 2-tiles-ahead prefetch with counted s_waitcnt vmcnt(8) (never drained
// mid-loop): each tile's 4 gload_lds/wave get ~2 tile-times of latency
// cover, and the 2-phase stage+drain lockstep (m233: ~72% of a 2-phase
// loop) amortizes across 16 iterations instead of 8.
// Swizzles (stage source XOR == read XOR, LDS dest linear):
//   K[32][256]: chunk c ^ (row&15)  -> 2-way read conflicts (free)
//   V[256][32]: chunk c ^ ((d>>1)&3)-> 2-way read conflicts (free)
// Wo fragments hoisted to registers BEFORE phase A (VGPRs free at 1 blk/CU).
// ---------------------------------------------------------------------------
__global__ __launch_bounds__(512) void attn_proj_ln(
    const __bf16* __restrict__ qb, const __bf16* __restrict__ kb,
    const __bf16* __restrict__ vt, const int* __restrict__ xb,
    const int* __restrict__ seg,
    const float* __restrict__ x, const __bf16* __restrict__ wo,
    const float* __restrict__ bo, const float* __restrict__ gamma,
    const float* __restrict__ beta, float* __restrict__ out)
{
  const int m0   = blockIdx.x * 16;
  const int h    = threadIdx.x >> 6;    // wave = head
  const int lane = threadIdx.x & 63;
  const int l15  = lane & 15;
  const int g    = lane >> 4;
  const int hd   = h * DH;
  const int qrow = m0 + l15;

  __shared__ __bf16 Kb[3][32 * 256];    // 3 x 16KB, swizzled chunks
  __shared__ __bf16 Vb[3][256 * 32];    // 3 x 16KB, swizzled chunks
  __shared__ __bf16 cl[16][264];        // ctx tile, padded stride
  __shared__ float redS[8][16];
  __shared__ float redQ[8][16];

  // hoist Wo fragments (phase B operands) into registers up front
  bf16x8 wf[2][8];
#pragma unroll
  for (int nt = 0; nt < 2; ++nt)
#pragma unroll
    for (int kk = 0; kk < 8; ++kk)
      wf[nt][kk] = *reinterpret_cast<const bf16x8*>(
          wo + (size_t)(h * 32 + nt * 16 + l15) * E + kk * 32 + 8 * g);

  // ======== phase A: attention ========
  {
    const int b  = xb[qrow];
    const int lo = seg[b];
    const int hi = seg[b + 1];

    const bf16x8 qf = *reinterpret_cast<const bf16x8*>(
        qb + (size_t)qrow * E + hd + g * 8);

    const int kstart = __shfl(lo, 0, 64);
    const int kend   = __shfl(hi, 15, 64);
    const int base   = kstart & ~31;
    const int nt_    = (kend - base + 31) >> 5;

    const int base_l = ((l15 & 12) << 1) + (l15 & 3);  // 8*(l15>>2) + (l15&3)
    const int h4g    = h * 4 + g;                      // K chunk (16B) index

    f32x4 acc0 = {0.f, 0.f, 0.f, 0.f};
    f32x4 acc1 = {0.f, 0.f, 0.f, 0.f};
    float lsum = 0.f;

#define STAGE32(BUF, J0)                                                       \
    {                                                                          \
      const int jj = (J0);                                                     \
      __bf16* kd = &Kb[(BUF)][0];                                              \
      __bf16* vd = &Vb[(BUF)][0];                                              \
      _Pragma("unroll")                                                        \
      for (int i_ = 0; i_ < 2; ++i_) {                                         \
        const int rr = 4 * h + 2 * i_ + (lane >> 5);                           \
        const int cc = lane & 31;                                              \
        GLOAD16(kb + (size_t)(jj + rr) * E + ((cc ^ (rr & 15)) * 8),           \
                kd + (4 * h + 2 * i_) * 256);                                  \
      }                                                                        \
      _Pragma("unroll")                                                        \
      for (int i_ = 0; i_ < 2; ++i_) {                                         \
        const int dd = 32 * h + 16 * i_ + (lane >> 2);                         \
        const int cc = lane & 3;                                               \
        GLOAD16(vt + (size_t)dd * N + jj + ((cc ^ ((dd >> 1) & 3)) * 8),       \
                vd + (32 * h + 16 * i_) * 32);                                 \
      }                                                                        \
    }

    asm volatile("s_waitcnt vmcnt(0)" ::: "memory");
    STAGE32(0, base)
    if (nt_ > 1) STAGE32(1, base + 32)

    for (int t = 0; t < nt_; ++t) {
      const int j0 = base + t * 32;
      const int bcur = t % 3;
      if (t + 2 < nt_) {
        STAGE32((t + 2) % 3, j0 + 64)
        asm volatile("s_waitcnt vmcnt(8)" ::: "memory");
      } else if (t + 1 < nt_) {
        asm volatile("s_waitcnt vmcnt(4)" ::: "memory");
      } else {
        asm volatile("s_waitcnt vmcnt(0)" ::: "memory");
      }
      __builtin_amdgcn_s_barrier();
      __builtin_amdgcn_sched_barrier(0);

      const __bf16* kc = &Kb[bcur][0];
      const __bf16* vc = &Vb[bcur][0];

      // ---- QK^T (swapped, permuted key IDs) ----
      const int r0 = base_l;
      const int r1 = base_l + 4;
      const bf16x8 kf0 = *reinterpret_cast<const bf16x8*>(
          kc + r0 * 256 + ((h4g ^ (r0 & 15)) * 8));
      const bf16x8 kf1 = *reinterpret_cast<const bf16x8*>(
          kc + r1 * 256 + ((h4g ^ (r1 & 15)) * 8));
      const f32x4 z = {0.f, 0.f, 0.f, 0.f};
      const f32x4 s0 = __builtin_amdgcn_mfma_f32_16x16x32_bf16(kf0, qf, z, 0, 0, 0);
      const f32x4 s1 = __builtin_amdgcn_mfma_f32_16x16x32_bf16(kf1, qf, z, 0, 0, 0);

      // ---- softmax numerators into the P A-fragment ----
      bf16x8 pa;
#pragma unroll
      for (int b_ = 0; b_ < 2; ++b_)
#pragma unroll
        for (int r = 0; r < 4; ++r) {
          const int key = j0 + 8 * g + 4 * b_ + r;
          const float sc = (b_ ? s1[r] : s0[r]) * CL;
          const float e  = (key >= lo && key < hi) ? EXP2F(sc) : 0.f;
          lsum += e;
          pa[4 * b_ + r] = (__bf16)e;
        }

      // ---- PV ----
      const int d0 = hd + l15;
      const int d1 = hd + 16 + l15;
      const bf16x8 vf0 = *reinterpret_cast<const bf16x8*>(
          vc + d0 * 32 + ((g ^ ((d0 >> 1) & 3)) * 8));
      const bf16x8 vf1 = *reinterpret_cast<const bf16x8*>(
          vc + d1 * 32 + ((g ^ ((d1 >> 1) & 3)) * 8));
      acc0 = __builtin_amdgcn_mfma_f32_16x16x32_bf16(pa, vf0, acc0, 0, 0, 0);
      acc1 = __builtin_amdgcn_mfma_f32_16x16x32_bf16(pa, vf1, acc1, 0, 0, 0);

      __builtin_amdgcn_sched_barrier(0);
      __builtin_amdgcn_s_barrier();
    }

    lsum += __shfl_xor(lsum, 16, 64);
    lsum += __shfl_xor(lsum, 32, 64);
    const float inv = 1.0f / lsum;
    float invr[4];
#pragma unroll
    for (int r = 0; r < 4; ++r) invr[r] = __shfl(inv, 4 * g + r, 64);

#pragma unroll
    for (int r = 0; r < 4; ++r) {
      cl[4 * g + r][hd + l15]      = (__bf16)(acc0[r] * invr[r]);
      cl[4 * g + r][hd + 16 + l15] = (__bf16)(acc1[r] * invr[r]);
    }
  }
  __syncthreads();

  // ======== phase B: projection + residual + LayerNorm ========
  {
    bf16x8 af[8];
#pragma unroll
    for (int kk = 0; kk < 8; ++kk)
      af[kk] = *reinterpret_cast<const bf16x8*>(&cl[l15][kk * 32 + 8 * g]);

    f32x4 acc[2];
    acc[0] = f32x4{0.f, 0.f, 0.f, 0.f};
    acc[1] = f32x4{0.f, 0.f, 0.f, 0.f};

#pragma unroll
    for (int kk = 0; kk < 8; ++kk)
#pragma unroll
      for (int nt = 0; nt < 2; ++nt)
        acc[nt] = __builtin_amdgcn_mfma_f32_16x16x32_bf16(af[kk], wf[nt][kk],
                                                          acc[nt], 0, 0, 0);

    float yv[2][4];
    float s1[4], s2[4];
#pragma unroll
    for (int r = 0; r < 4; ++r) { s1[r] = 0.f; s2[r] = 0.f; }
#pragma unroll
    for (int nt = 0; nt < 2; ++nt) {
      const int c = h * 32 + nt * 16 + l15;
      const float bb = bo[c];
#pragma unroll
      for (int r = 0; r < 4; ++r) {
        const int row = m0 + 4 * g + r;
        const float y = acc[nt][r] + bb + x[(size_t)row * E + c];
        yv[nt][r] = y;
        s1[r] += y;
        s2[r] += y * y;
      }
    }
#pragma unroll
    for (int off = 1; off < 16; off <<= 1) {
#pragma unroll
      for (int r = 0; r < 4; ++r) {
        s1[r] += __shfl_xor(s1[r], off, 64);
        s2[r] += __shfl_xor(s2[r], off, 64);
      }
    }
    if (l15 == 0) {
#pragma unroll
      for (int r = 0; r < 4; ++r) {
        redS[h][4 * g + r] = s1[r];
        redQ[h][4 * g + r] = s2[r];
      }
    }
    __syncthreads();
    float mu[4], rs[4];
#pragma unroll
    for (int r = 0; r < 4; ++r) {
      float ts = 0.f, tq = 0.f;
#pragma unroll
      for (int w = 0; w < 8; ++w) { ts += redS[w][4 * g + r]; tq += redQ[w][4 * g + r]; }
      mu[r] = ts * (1.0f / E);
      const float var = tq * (1.0f / E) - mu[r] * mu[r];
      rs[r] = rsqrtf(var + 1e-5f);
    }
#pragma unroll
    for (int nt = 0; nt < 2; ++nt) {
      const int c = h * 32 + nt * 16 + l15;
      const float gg = gamma[c];
      const float bt = beta[c];
#pragma unroll
      for (int r = 0; r < 4; ++r) {
        const int row = m0 + 4 * g + r;
        out[(size_t)row * E + c] = (yv[nt][r] - mu[r]) * rs[r] * gg + bt;
      }
    }
  }
}

}  // namespace

extern "C" void kernel_launch(void* const* d_in, const int* in_sizes, int n_in,
                              void* d_out, int out_size, void* d_ws, size_t ws_size,
                              hipStream_t stream) {
  const float* x     = (const float*)d_in[0];
  const float* pe    = (const float*)d_in[1];
  const int*   xb    = (const int*)d_in[2];
  const float* Wq    = (const float*)d_in[3];
  const float* Wk    = (const float*)d_in[4];
  const float* Wv    = (const float*)d_in[5];
  const float* bq    = (const float*)d_in[6];
  const float* bk    = (const float*)d_in[7];
  const float* bv    = (const float*)d_in[8];
  const float* Wo    = (const float*)d_in[9];
  const float* bo    = (const float*)d_in[10];
  const float* gamma = (const float*)d_in[11];
  const float* beta  = (const float*)d_in[12];
  float* out = (float*)d_out;

  char* wsb = (char*)d_ws;
  const size_t NE = (size_t)N * E;          // 1,048,576 elements
  __bf16* qb16  = (__bf16*)(wsb);                   // 2 MB
  __bf16* kb16  = (__bf16*)(wsb + 2 * NE);          // 2 MB
  __bf16* vt16  = (__bf16*)(wsb + 4 * NE);          // 2 MB  [E][N]
  __bf16* xpe16 = (__bf16*)(wsb + 6 * NE);          // 2 MB
  __bf16* xv16  = (__bf16*)(wsb + 8 * NE);          // 2 MB
  __bf16* wb16  = (__bf16*)(wsb + 10 * NE);         // 512 KB (4 mats)
  int*    seg   = (int*)(wsb + 10 * NE + 4 * (size_t)E * E * 2);

  prep_kernel<<<dim3(641), 256, 0, stream>>>(x, pe, xb, Wq, Wk, Wv, Wo,
                                             xpe16, xv16, wb16, seg);
  qkv_mfma<<<dim3(512, 3), 256, 0, stream>>>(xpe16, xv16, wb16, bq, bk, bv,
                                             qb16, kb16, vt16);
  attn_proj_ln<<<dim3(256), 512, 0, stream>>>(qb16, kb16, vt16, xb, seg,
                                              x, wb16 + 3 * (size_t)E * E,
                                              bo, gamma, beta, out);
}

// Round 12
// 38.516 us; speedup vs baseline: 1.7849x; 1.7849x over previous
//
#include <hip/hip_runtime.h>
#include <math.h>

namespace {

constexpr int N  = 4096;
constexpr int E  = 256;
constexpr int H  = 8;
constexpr int DH = 32;
constexpr int BS = 8;
// fold 1/sqrt(DH) and log2(e): softmax in exp2 domain, no max subtraction
// (f32-safe: |s*CL| realistic max ~16, overflow at 127 -> 27 sigma margin)
constexpr float CL = 0.17677669529663687f * 1.4426950408889634f;

typedef __bf16 bf16x8 __attribute__((ext_vector_type(8)));
typedef __bf16 bf16x4 __attribute__((ext_vector_type(4)));
typedef float  f32x4  __attribute__((ext_vector_type(4)));

#if __has_builtin(__builtin_amdgcn_exp2f)
#define EXP2F(x) __builtin_amdgcn_exp2f(x)
#else
#define EXP2F(x) __expf((x) * 0.6931471805599453f)
#endif

__device__ inline bf16x8 pack8(float4 a, float4 b) {
  bf16x8 r;
  r[0] = (__bf16)a.x; r[1] = (__bf16)a.y; r[2] = (__bf16)a.z; r[3] = (__bf16)a.w;
  r[4] = (__bf16)b.x; r[5] = (__bf16)b.y; r[6] = (__bf16)b.z; r[7] = (__bf16)b.w;
  return r;
}

// ===========================================================================
// FRAGMENT-MAJOR LAYOUTS (the whole point of this round):
// every MFMA operand lives in memory as [frag][lane(64)][elem(8)] so the
// consuming wave loads it as ONE coalesced 1KB instruction (16B/lane),
// instead of a 16-row x 512B-stride gather (~16 txns). frag element address
// is always  base + frag_id*512 + lane*8.
//   xpe/xv : frag_id = rowtile(256)*8 + ktile(8);   lane=(tok&15)+16g, k=32kt+8g+i
//   wfrag  : per mat, frag_id = n16(16)*8 + ktile;  lane=(n&15)+16g
//   qfrag  : frag_id = (head*256 + rowtile)         lane=(tok&15)+16g', e=32h+8g'+i
//   kfrag  : frag_id = (head*64 + keytile64)*4 + mt with the r5 key-ID
//            permutation baked in: slot m holds key 64t+8(m>>2)+(m&3)+32(mt>>1)+4(mt&1)
//   vfrag  : frag_id = ((head*64+keytile64)*2+ks)*2+dh; lane=(d&15)+16g',
//            elem i = key&7  (keys 64t+32ks+8g'+i)
// ===========================================================================

// ---------------------------------------------------------------------------
// prep: fragment-major bf16 conversion of x+pe, x, and the 4 weight mats.
//  blocks [0,512):   4 waves each: wave wid = rt*8+kt -> xpe_frag & xv_frag
//  blocks [512,640): wave wid -> one W fragment (mat = wid>>7)
//  block 640:        seg via binary search
// ---------------------------------------------------------------------------
__global__ __launch_bounds__(256) void prep_kernel(
    const float* __restrict__ x, const float* __restrict__ pe,
    const int* __restrict__ xb,
    const float* __restrict__ Wq, const float* __restrict__ Wk,
    const float* __restrict__ Wv, const float* __restrict__ Wo,
    __bf16* __restrict__ xpef, __bf16* __restrict__ xvf,
    __bf16* __restrict__ wfrag, int* __restrict__ seg)
{
  const int bid  = blockIdx.x;
  const int wv4  = threadIdx.x >> 6;
  const int lane = threadIdx.x & 63;
  const int l15  = lane & 15, g = lane >> 4;

  if (bid < 512) {
    const int wid = bid * 4 + wv4;            // = rt*8 + kt
    const int rt = wid >> 3, kt = wid & 7;
    const float* xr = x  + (size_t)(rt * 16 + l15) * E + kt * 32 + 8 * g;
    const float* pr = pe + (size_t)(rt * 16 + l15) * E + kt * 32 + 8 * g;
    float4 a0 = *(const float4*)xr;
    float4 a1 = *(const float4*)(xr + 4);
    const float4 p0 = *(const float4*)pr;
    const float4 p1 = *(const float4*)(pr + 4);
    *reinterpret_cast<bf16x8*>(xvf + (size_t)wid * 512 + lane * 8) = pack8(a0, a1);
    a0.x += p0.x; a0.y += p0.y; a0.z += p0.z; a0.w += p0.w;
    a1.x += p1.x; a1.y += p1.y; a1.z += p1.z; a1.w += p1.w;
    *reinterpret_cast<bf16x8*>(xpef + (size_t)wid * 512 + lane * 8) = pack8(a0, a1);
  } else if (bid < 640) {
    const int wid = (bid - 512) * 4 + wv4;    // [0,512)
    const int mat = wid >> 7;
    const int rem = wid & 127;                // n16*8 + kt
    const int n16 = rem >> 3, kt = rem & 7;
    const float* __restrict__ W =
        (mat == 0) ? Wq : (mat == 1) ? Wk : (mat == 2) ? Wv : Wo;
    const float* wr = W + (size_t)(n16 * 16 + l15) * E + kt * 32 + 8 * g;
    *reinterpret_cast<bf16x8*>(wfrag + (size_t)wid * 512 + lane * 8) =
        pack8(*(const float4*)wr, *(const float4*)(wr + 4));
  } else {
    if (threadIdx.x <= BS) {
      const int t = threadIdx.x;
      int lo = 0, hi = N;
      while (lo < hi) { int mid = (lo + hi) >> 1; if (xb[mid] < t) lo = mid + 1; else hi = mid; }
      seg[t] = lo;
    }
  }
}

// ---------------------------------------------------------------------------
// MFMA QKV from fragment-major operands: out = A @ W^T + b.
// Block = 16 rows x 128 cols, 4 waves (32-col slices), grid (512,3).
// All 24 loads per wave are coalesced 1KB frag loads; zero LDS, no barriers.
// Epilogue scatters acc (+bias) directly into q/k/vfrag layouts.
// ---------------------------------------------------------------------------
__global__ __launch_bounds__(256) void qkv_mfma(
    const __bf16* __restrict__ xpef, const __bf16* __restrict__ xvf,
    const __bf16* __restrict__ wfrag,
    const float* __restrict__ bq, const float* __restrict__ bk,
    const float* __restrict__ bv,
    __bf16* __restrict__ qfrag, __bf16* __restrict__ kfrag,
    __bf16* __restrict__ vfrag)
{
  const int mat  = blockIdx.y;
  const int rt   = blockIdx.x >> 1;
  const int half = blockIdx.x & 1;
  const int wv   = threadIdx.x >> 6;
  const int lane = threadIdx.x & 63;
  const int l15  = lane & 15, g = lane >> 4;
  const int m0   = rt * 16;
  const int cb0  = half * 128 + wv * 32;

  const __bf16* __restrict__ A = (mat < 2) ? xpef : xvf;
  const __bf16* __restrict__ W = wfrag + (size_t)mat * 65536;

  bf16x8 af[8];
#pragma unroll
  for (int kk = 0; kk < 8; ++kk)
    af[kk] = *reinterpret_cast<const bf16x8*>(A + (size_t)(rt * 8 + kk) * 512 + lane * 8);

  f32x4 acc0 = {0.f, 0.f, 0.f, 0.f};
  f32x4 acc1 = {0.f, 0.f, 0.f, 0.f};
  const int n16b = cb0 >> 4;
#pragma unroll
  for (int kk = 0; kk < 8; ++kk) {
    const bf16x8 wf0 = *reinterpret_cast<const bf16x8*>(
        W + (size_t)(n16b * 8 + kk) * 512 + lane * 8);
    const bf16x8 wf1 = *reinterpret_cast<const bf16x8*>(
        W + (size_t)((n16b + 1) * 8 + kk) * 512 + lane * 8);
    acc0 = __builtin_amdgcn_mfma_f32_16x16x32_bf16(wf0, af[kk], acc0, 0, 0, 0);
    acc1 = __builtin_amdgcn_mfma_f32_16x16x32_bf16(wf1, af[kk], acc1, 0, 0, 0);
  }

  const int token = m0 + l15;
  const f32x4 accs[2] = {acc0, acc1};

  if (mat < 2) {
    const float* __restrict__ bi = mat ? bk : bq;
    __bf16* __restrict__ dst = mat ? kfrag : qfrag;
#pragma unroll
    for (int nt = 0; nt < 2; ++nt) {
      const int e  = cb0 + nt * 16 + 4 * g;   // 4 consecutive dims r=0..3
      const float4 bb = *(const float4*)(bi + e);
      const int h  = e >> 5;
      const int gp = (e & 31) >> 3;
      const int ib = e & 7;                   // 4*(g&1)
      bf16x4 o;
      o.x = (__bf16)(accs[nt][0] + bb.x);
      o.y = (__bf16)(accs[nt][1] + bb.y);
      o.z = (__bf16)(accs[nt][2] + bb.z);
      o.w = (__bf16)(accs[nt][3] + bb.w);
      size_t idx;
      if (mat == 0) {
        const int lp = (token & 15) + 16 * gp;
        idx = ((size_t)(h * 256 + rt) * 64 + lp) * 8 + ib;
      } else {
        const int t  = token >> 6, tk = token & 63;
        const int mt = 2 * (tk >> 5) + ((tk >> 2) & 1);
        const int lp = 4 * ((tk >> 3) & 3) + (tk & 3) + 16 * gp;
        idx = ((size_t)((h * 64 + t) * 4 + mt) * 64 + lp) * 8 + ib;
      }
      *reinterpret_cast<bf16x4*>(dst + idx) = o;
    }
  } else {
    const int t  = token >> 6, tk = token & 63;
    const int ks = (tk >> 5) & 1;
    const int gp = (tk >> 3) & 3;
    const int i  = tk & 7;
#pragma unroll
    for (int nt = 0; nt < 2; ++nt) {
      const int e0 = cb0 + nt * 16 + 4 * g;
      const float4 bb = *(const float4*)(bv + e0);
      const float bbr[4] = {bb.x, bb.y, bb.z, bb.w};
#pragma unroll
      for (int r = 0; r < 4; ++r) {
        const int d  = e0 + r;
        const int h  = d >> 5, dh = (d >> 4) & 1;
        const size_t idx =
            ((size_t)(((h * 64 + t) * 2 + ks) * 2 + dh) * 64 + (d & 15) + 16 * gp) * 8 + i;
        vfrag[idx] = (__bf16)(accs[nt][r] + bbr[r]);
      }
    }
  }
}

// ---------------------------------------------------------------------------
// Fused attention + projection + residual + LayerNorm, fragment-major.
// Block = 16 query rows, 512 threads = 8 waves, wave = head.
// Phase A: free-running key loop (NO LDS staging, NO barriers, no vmcnt):
//   every kf/vf/qf load is one coalesced 1KB instruction from the frag
//   arrays; permuted key IDs are baked into kfrag so the S^T accumulator
//   regs are directly the P A-fragment slots; fixed-base exp2 softmax.
// Phase B: proven proj+LN, Wo read coalesced from wfrag[3].
// ---------------------------------------------------------------------------
__global__ __launch_bounds__(512) void attn_proj_ln(
    const __bf16* __restrict__ qfrag, const __bf16* __restrict__ kfrag,
    const __bf16* __restrict__ vfrag, const int* __restrict__ xb,
    const int* __restrict__ seg,
    const float* __restrict__ x, const __bf16* __restrict__ wofrag,
    const float* __restrict__ bo, const float* __restrict__ gamma,
    const float* __restrict__ beta, float* __restrict__ out)
{
  const int rt   = blockIdx.x;
  const int m0   = rt * 16;
  const int h    = threadIdx.x >> 6;    // wave = head
  const int lane = threadIdx.x & 63;
  const int l15  = lane & 15;
  const int g    = lane >> 4;
  const int qrow = m0 + l15;

  __shared__ __bf16 cl[16][264];        // ctx tile, padded stride
  __shared__ float redS[8][16];
  __shared__ float redQ[8][16];

  // ======== phase A: attention ========
  {
    const int b  = xb[qrow];
    const int lo = seg[b];
    const int hi = seg[b + 1];

    const bf16x8 qf = *reinterpret_cast<const bf16x8*>(
        qfrag + (size_t)(h * 256 + rt) * 512 + lane * 8);

    const int kstart = __shfl(lo, 0, 64);
    const int kend   = __shfl(hi, 15, 64);

    f32x4 acc0 = {0.f, 0.f, 0.f, 0.f};
    f32x4 acc1 = {0.f, 0.f, 0.f, 0.f};
    float lsum = 0.f;

    for (int t = kstart >> 6; t * 64 < kend; ++t) {
      const int j0 = t * 64;
      const __bf16* kb4 = kfrag + (size_t)(h * 64 + t) * 2048 + lane * 8;
      const __bf16* vb4 = vfrag + (size_t)(h * 64 + t) * 2048 + lane * 8;

      const bf16x8 kf0 = *reinterpret_cast<const bf16x8*>(kb4);
      const bf16x8 kf1 = *reinterpret_cast<const bf16x8*>(kb4 + 512);
      const bf16x8 kf2 = *reinterpret_cast<const bf16x8*>(kb4 + 1024);
      const bf16x8 kf3 = *reinterpret_cast<const bf16x8*>(kb4 + 1536);
      const bf16x8 vf00 = *reinterpret_cast<const bf16x8*>(vb4);          // ks0,dh0
      const bf16x8 vf01 = *reinterpret_cast<const bf16x8*>(vb4 + 512);    // ks0,dh1
      const bf16x8 vf10 = *reinterpret_cast<const bf16x8*>(vb4 + 1024);   // ks1,dh0
      const bf16x8 vf11 = *reinterpret_cast<const bf16x8*>(vb4 + 1536);   // ks1,dh1

      const f32x4 z = {0.f, 0.f, 0.f, 0.f};
      f32x4 s[4];
      s[0] = __builtin_amdgcn_mfma_f32_16x16x32_bf16(kf0, qf, z, 0, 0, 0);
      s[1] = __builtin_amdgcn_mfma_f32_16x16x32_bf16(kf1, qf, z, 0, 0, 0);
      s[2] = __builtin_amdgcn_mfma_f32_16x16x32_bf16(kf2, qf, z, 0, 0, 0);
      s[3] = __builtin_amdgcn_mfma_f32_16x16x32_bf16(kf3, qf, z, 0, 0, 0);

      bf16x8 pa[2];
#pragma unroll
      for (int ks = 0; ks < 2; ++ks)
#pragma unroll
        for (int b_ = 0; b_ < 2; ++b_)
#pragma unroll
          for (int r = 0; r < 4; ++r) {
            const int key = j0 + 32 * ks + 8 * g + 4 * b_ + r;
            const float sc = s[2 * ks + b_][r] * CL;
            const float e  = (key >= lo && key < hi) ? EXP2F(sc) : 0.f;
            lsum += e;
            pa[ks][4 * b_ + r] = (__bf16)e;
          }

      acc0 = __builtin_amdgcn_mfma_f32_16x16x32_bf16(pa[0], vf00, acc0, 0, 0, 0);
      acc1 = __builtin_amdgcn_mfma_f32_16x16x32_bf16(pa[0], vf01, acc1, 0, 0, 0);
      acc0 = __builtin_amdgcn_mfma_f32_16x16x32_bf16(pa[1], vf10, acc0, 0, 0, 0);
      acc1 = __builtin_amdgcn_mfma_f32_16x16x32_bf16(pa[1], vf11, acc1, 0, 0, 0);
    }

    lsum += __shfl_xor(lsum, 16, 64);
    lsum += __shfl_xor(lsum, 32, 64);
    const float inv = 1.0f / lsum;
    float invr[4];
#pragma unroll
    for (int r = 0; r < 4; ++r) invr[r] = __shfl(inv, 4 * g + r, 64);

#pragma unroll
    for (int r = 0; r < 4; ++r) {
      cl[4 * g + r][h * DH + l15]      = (__bf16)(acc0[r] * invr[r]);
      cl[4 * g + r][h * DH + 16 + l15] = (__bf16)(acc1[r] * invr[r]);
    }
  }
  __syncthreads();

  // ======== phase B: projection + residual + LayerNorm ========
  {
    bf16x8 af[8];
#pragma unroll
    for (int kk = 0; kk < 8; ++kk)
      af[kk] = *reinterpret_cast<const bf16x8*>(&cl[l15][kk * 32 + 8 * g]);

    f32x4 acc[2];
    acc[0] = f32x4{0.f, 0.f, 0.f, 0.f};
    acc[1] = f32x4{0.f, 0.f, 0.f, 0.f};

#pragma unroll
    for (int kk = 0; kk < 8; ++kk)
#pragma unroll
      for (int nt = 0; nt < 2; ++nt) {
        const bf16x8 wf = *reinterpret_cast<const bf16x8*>(
            wofrag + (size_t)((h * 2 + nt) * 8 + kk) * 512 + lane * 8);
        acc[nt] = __builtin_amdgcn_mfma_f32_16x16x32_bf16(af[kk], wf, acc[nt], 0, 0, 0);
      }

    float yv[2][4];
    float s1[4], s2[4];
#pragma unroll
    for (int r = 0; r < 4; ++r) { s1[r] = 0.f; s2[r] = 0.f; }
#pragma unroll
    for (int nt = 0; nt < 2; ++nt) {
      const int c = h * 32 + nt * 16 + l15;
      const float bb = bo[c];
#pragma unroll
      for (int r = 0; r < 4; ++r) {
        const int row = m0 + 4 * g + r;
        const float y = acc[nt][r] + bb + x[(size_t)row * E + c];
        yv[nt][r] = y;
        s1[r] += y;
        s2[r] += y * y;
      }
    }
#pragma unroll
    for (int off = 1; off < 16; off <<= 1) {
#pragma unroll
      for (int r = 0; r < 4; ++r) {
        s1[r] += __shfl_xor(s1[r], off, 64);
        s2[r] += __shfl_xor(s2[r], off, 64);
      }
    }
    if (l15 == 0) {
#pragma unroll
      for (int r = 0; r < 4; ++r) {
        redS[h][4 * g + r] = s1[r];
        redQ[h][4 * g + r] = s2[r];
      }
    }
    __syncthreads();
    float mu[4], rs[4];
#pragma unroll
    for (int r = 0; r < 4; ++r) {
      float ts = 0.f, tq = 0.f;
#pragma unroll
      for (int w = 0; w < 8; ++w) { ts += redS[w][4 * g + r]; tq += redQ[w][4 * g + r]; }
      mu[r] = ts * (1.0f / E);
      const float var = tq * (1.0f / E) - mu[r] * mu[r];
      rs[r] = rsqrtf(var + 1e-5f);
    }
#pragma unroll
    for (int nt = 0; nt < 2; ++nt) {
      const int c = h * 32 + nt * 16 + l15;
      const float gg = gamma[c];
      const float bt = beta[c];
#pragma unroll
      for (int r = 0; r < 4; ++r) {
        const int row = m0 + 4 * g + r;
        out[(size_t)row * E + c] = (yv[nt][r] - mu[r]) * rs[r] * gg + bt;
      }
    }
  }
}

}  // namespace

extern "C" void kernel_launch(void* const* d_in, const int* in_sizes, int n_in,
                              void* d_out, int out_size, void* d_ws, size_t ws_size,
                              hipStream_t stream) {
  const float* x     = (const float*)d_in[0];
  const float* pe    = (const float*)d_in[1];
  const int*   xb    = (const int*)d_in[2];
  const float* Wq    = (const float*)d_in[3];
  const float* Wk    = (const float*)d_in[4];
  const float* Wv    = (const float*)d_in[5];
  const float* bq    = (const float*)d_in[6];
  const float* bk    = (const float*)d_in[7];
  const float* bv    = (const float*)d_in[8];
  const float* Wo    = (const float*)d_in[9];
  const float* bo    = (const float*)d_in[10];
  const float* gamma = (const float*)d_in[11];
  const float* beta  = (const float*)d_in[12];
  float* out = (float*)d_out;

  __bf16* ws = (__bf16*)d_ws;
  const size_t NE = (size_t)N * E;          // 1,048,576 elements
  __bf16* qfrag = ws;                       // 2 MB
  __bf16* kfrag = ws + NE;                  // 2 MB
  __bf16* vfrag = ws + 2 * NE;              // 2 MB
  __bf16* xpef  = ws + 3 * NE;              // 2 MB
  __bf16* xvf   = ws + 4 * NE;              // 2 MB
  __bf16* wfrag = ws + 5 * NE;              // 512 KB (4 mats x 65536)
  int*    seg   = (int*)(ws + 5 * NE + 4 * 65536);

  prep_kernel<<<dim3(641), 256, 0, stream>>>(x, pe, xb, Wq, Wk, Wv, Wo,
                                             xpef, xvf, wfrag, seg);
  qkv_mfma<<<dim3(512, 3), 256, 0, stream>>>(xpef, xvf, wfrag, bq, bk, bv,
                                             qfrag, kfrag, vfrag);
  attn_proj_ln<<<dim3(256), 512, 0, stream>>>(qfrag, kfrag, vfrag, xb, seg,
                                              x, wfrag + 3 * 65536,
                                              bo, gamma, beta, out);
}